// Round 1
// baseline (223.441 us; speedup 1.0000x reference)
//
#include <hip/hip_runtime.h>

// DepthToSpace: in [8, 64, 256, 256] f32 -> out [8, 4, 1024, 1024] f32
// out[b, s, h*4+r, w*4+c] = in[b, s*16 + r*4 + c, h, w]
//
// One thread per output float4 (4 consecutive ww => same h,r, c=0..3, w=ww/4).
// Reads: 4 scalar loads, each coalesced across the wave (lane i -> w = w0+i).
// Write: one float4, perfectly contiguous across the wave (1 KiB/store/wave).

#define TOTAL_ELEMS (8 * 64 * 256 * 256)   // 33,554,432
#define TOTAL_F4    (TOTAL_ELEMS / 4)      // 8,388,608
#define CH_STRIDE   65536                  // H*W floats

__global__ __launch_bounds__(256) void DepthToSpace_8486855377460_kernel(
    const float* __restrict__ in, float* __restrict__ out) {
    int idx4 = blockIdx.x * blockDim.x + threadIdx.x;  // output float4 index
    int base = idx4 << 2;                              // output float index (< 2^25, int ok)

    int ww = base & 1023;          // output col, multiple of 4
    int hh = (base >> 10) & 1023;  // output row
    int s  = (base >> 20) & 3;     // split group
    int b  = base >> 22;           // batch

    int w = ww >> 2;
    int r = hh & 3;
    int h = hh >> 2;
    int c = (s << 4) + (r << 2);   // base channel of the 4-channel gather

    int in_off = (((b << 6) + c) << 16) + (h << 8) + w;  // ((b*64+c)*65536) + h*256 + w

    float4 v;
    v.x = in[in_off];
    v.y = in[in_off + 1 * CH_STRIDE];
    v.z = in[in_off + 2 * CH_STRIDE];
    v.w = in[in_off + 3 * CH_STRIDE];

    reinterpret_cast<float4*>(out)[idx4] = v;
}

extern "C" void kernel_launch(void* const* d_in, const int* in_sizes, int n_in,
                              void* d_out, int out_size, void* d_ws, size_t ws_size,
                              hipStream_t stream) {
    const float* x = (const float*)d_in[0];
    float* out = (float*)d_out;
    dim3 block(256);
    dim3 grid(TOTAL_F4 / 256);  // 32768 blocks
    DepthToSpace_8486855377460_kernel<<<grid, block, 0, stream>>>(x, out);
}